// Round 1
// baseline (1280.631 us; speedup 1.0000x reference)
//
#include <hip/hip_runtime.h>
#include <stdint.h>

// Problem: x is [8192, 24576] fp32. out[i,j] = relu(x[i,j]) if x[i,j] is among
// the top-64 of row i (ties -> smaller index), else 0.
//
// One block per row, 512 threads, 48 elements/thread held in registers as
// order-preserving uint32 keys. Exact 64th-largest key via 3-phase radix
// select (2048-bin LDS histogram + reduction tree + descent). Rare partial-tie
// path does an index radix select for exact jax.lax.top_k tie semantics.

#define ROWLEN 24576
#define TPB    512
#define CHUNKS 12            // ROWLEN / 4 / TPB
#define ELEMS  48            // CHUNKS * 4
#define TOPK   64

__device__ __forceinline__ unsigned enc_key(float f) {
    unsigned u = __float_as_uint(f);
    // monotonic map: negative -> ~u, positive -> u | signbit
    return (u & 0x80000000u) ? ~u : (u | 0x80000000u);
}

// tree level l (1..11) lives at offset 2048 - (4096 >> l), size 2048 >> l
__device__ __forceinline__ int lvl_off(int l) { return 2048 - (4096 >> l); }

// Build 11-level sum tree over hist[2048], then thread 0 descends to find the
// bin containing the rank-th element (largest-first, or smallest-first for
// the index-tie phase). Results broadcast via s_bin / s_rank.
// Must be called from block-uniform control flow.
__device__ void build_and_descend(unsigned* hist, unsigned* tree, int tid,
                                  bool smallest_first, unsigned rank,
                                  volatile unsigned* s_bin,
                                  volatile unsigned* s_rank) {
    for (int l = 1; l <= 11; ++l) {
        int n = 2048 >> l;
        unsigned* src = (l == 1) ? hist : (tree + lvl_off(l - 1));
        unsigned* dst = tree + lvl_off(l);
        for (int i = tid; i < n; i += TPB) dst[i] = src[2 * i] + src[2 * i + 1];
        __syncthreads();
    }
    if (tid == 0) {
        unsigned R = rank;
        int node = 0;
        for (int l = 11; l >= 1; --l) {
            const unsigned* child = (l == 1) ? hist : (tree + lvl_off(l - 1));
            unsigned left  = child[2 * node];
            unsigned right = child[2 * node + 1];
            if (smallest_first) {
                if (R <= left) { node = 2 * node; } else { R -= left; node = 2 * node + 1; }
            } else {
                if (R <= right) { node = 2 * node + 1; } else { R -= right; node = 2 * node; }
            }
        }
        *s_bin  = (unsigned)node;
        *s_rank = R;
    }
    __syncthreads();
}

__device__ __forceinline__ float out_val(unsigned k, unsigned idx,
                                         unsigned Tkey, unsigned C) {
    bool sel = (k > Tkey) || (k == Tkey && idx <= C);
    // positive originals have key > 0x80000000 (0x80000000 == +0.0 -> relu 0)
    return (sel && k > 0x80000000u) ? __uint_as_float(k ^ 0x80000000u) : 0.0f;
}

__global__ __launch_bounds__(TPB, 4)
void topk_scatter_kernel(const float* __restrict__ x, float* __restrict__ out,
                         int nrows) {
    __shared__ unsigned hist[2048];
    __shared__ unsigned tree[2047];
    __shared__ unsigned s_bin, s_rank, s_cnt, s_C;
    __shared__ unsigned cand[16];

    int row = blockIdx.x;
    if (row >= nrows) return;
    int tid = threadIdx.x;

    const float4* rowp = (const float4*)(x + (size_t)row * ROWLEN);
    float4*       outp = (float4*)(out + (size_t)row * ROWLEN);

    // ---- single HBM read pass: keys into registers
    unsigned keys[ELEMS];
#pragma unroll
    for (int c = 0; c < CHUNKS; ++c) {
        float4 v = rowp[c * TPB + tid];
        keys[4 * c + 0] = enc_key(v.x);
        keys[4 * c + 1] = enc_key(v.y);
        keys[4 * c + 2] = enc_key(v.z);
        keys[4 * c + 3] = enc_key(v.w);
    }

    // ---- phase 1: top 11 bits
    for (int i = tid; i < 2048; i += TPB) hist[i] = 0;
    __syncthreads();
#pragma unroll
    for (int e = 0; e < ELEMS; ++e) atomicAdd(&hist[keys[e] >> 21], 1u);
    __syncthreads();
    build_and_descend(hist, tree, tid, false, TOPK, &s_bin, &s_rank);
    unsigned B1 = s_bin, R1 = s_rank;

    // ---- phase 2: middle 11 bits (bits 20..10)
    for (int i = tid; i < 2048; i += TPB) hist[i] = 0;
    __syncthreads();
#pragma unroll
    for (int e = 0; e < ELEMS; ++e)
        if ((keys[e] >> 21) == B1) atomicAdd(&hist[(keys[e] >> 10) & 0x7FFu], 1u);
    __syncthreads();
    build_and_descend(hist, tree, tid, false, R1, &s_bin, &s_rank);
    unsigned B2 = s_bin, R2 = s_rank;

    // ---- phase 3: low 10 bits
    unsigned pref22 = (B1 << 11) | B2;
    for (int i = tid; i < 2048; i += TPB) hist[i] = 0;
    __syncthreads();
#pragma unroll
    for (int e = 0; e < ELEMS; ++e)
        if ((keys[e] >> 10) == pref22) atomicAdd(&hist[keys[e] & 0x3FFu], 1u);
    __syncthreads();
    build_and_descend(hist, tree, tid, false, R2, &s_bin, &s_rank);
    unsigned B3 = s_bin, R3 = s_rank;
    unsigned eqcnt = hist[B3];               // # elements with key == Tkey
    unsigned Tkey  = (B1 << 21) | (B2 << 10) | B3;

    unsigned C = 0xFFFFFFFFu;                // index cutoff among ties
    if (R3 < eqcnt) {
        // ---- rare partial-tie path: need R3-th smallest index among equals
        __syncthreads();                     // protect hist[B3] reads above
        for (int i = tid; i < 2048; i += TPB) hist[i] = 0;
        if (tid == 0) s_cnt = 0;
        __syncthreads();
#pragma unroll
        for (int e = 0; e < ELEMS; ++e) {
            if (keys[e] == Tkey) {
                unsigned idx = ((unsigned)((e / 4) * TPB + tid)) * 4u + (e & 3);
                atomicAdd(&hist[idx >> 4], 1u);   // idx < 24576 -> bin < 1536
            }
        }
        __syncthreads();
        build_and_descend(hist, tree, tid, true, R3, &s_bin, &s_rank);
        unsigned B4 = s_bin, r4 = s_rank;
#pragma unroll
        for (int e = 0; e < ELEMS; ++e) {
            if (keys[e] == Tkey) {
                unsigned idx = ((unsigned)((e / 4) * TPB + tid)) * 4u + (e & 3);
                if ((idx >> 4) == B4) {
                    unsigned p = atomicAdd(&s_cnt, 1u);
                    if (p < 16u) cand[p] = idx;   // <=16 distinct indices/bin
                }
            }
        }
        __syncthreads();
        if (tid == 0) {
            unsigned n = s_cnt; if (n > 16u) n = 16u;
            for (unsigned a = 0; a + 1 < n; ++a)       // tiny selection sort
                for (unsigned b = a + 1; b < n; ++b)
                    if (cand[b] < cand[a]) { unsigned t = cand[a]; cand[a] = cand[b]; cand[b] = t; }
            s_C = cand[r4 - 1];
        }
        __syncthreads();
        C = s_C;
    }

    // ---- single HBM write pass
#pragma unroll
    for (int c = 0; c < CHUNKS; ++c) {
        unsigned base = ((unsigned)(c * TPB + tid)) * 4u;
        float4 o;
        o.x = out_val(keys[4 * c + 0], base + 0u, Tkey, C);
        o.y = out_val(keys[4 * c + 1], base + 1u, Tkey, C);
        o.z = out_val(keys[4 * c + 2], base + 2u, Tkey, C);
        o.w = out_val(keys[4 * c + 3], base + 3u, Tkey, C);
        outp[c * TPB + tid] = o;
    }
}

extern "C" void kernel_launch(void* const* d_in, const int* in_sizes, int n_in,
                              void* d_out, int out_size, void* d_ws, size_t ws_size,
                              hipStream_t stream) {
    const float* x = (const float*)d_in[0];
    float* out = (float*)d_out;
    int nrows = in_sizes[0] / ROWLEN;   // 8192
    topk_scatter_kernel<<<nrows, TPB, 0, stream>>>(x, out, nrows);
}